// Round 1
// baseline (582.054 us; speedup 1.0000x reference)
//
#include <hip/hip_runtime.h>
#include <hip/hip_bf16.h>

typedef __bf16 bf16;
typedef __bf16 bf16x8 __attribute__((ext_vector_type(8)));
typedef float f32x4 __attribute__((ext_vector_type(4)));
typedef unsigned short ushort8_t __attribute__((ext_vector_type(8)));

// Problem constants
// B=4, S=4096, H=1024, G=256, W=8, CHUNK=1024, NUM_HEADS=4, hd=256
// M = B*S = 16384 rows, NC = 16 chunks

// ---------------- wavelet kernel normalization ----------------
__global__ __launch_bounds__(256) void k_wavelet(const float* __restrict__ mw,
                                                 const float* __restrict__ sc,
                                                 float* __restrict__ kern) {
    int w = blockIdx.x;
    int tid = threadIdx.x;
    float s = 0.f;
    for (int h = tid; h < 1024; h += 256) { float v = mw[w * 1024 + h]; s += v * v; }
#pragma unroll
    for (int xm = 1; xm < 64; xm <<= 1) s += __shfl_xor(s, xm);
    __shared__ float red[4];
    if ((tid & 63) == 0) red[tid >> 6] = s;
    __syncthreads();
    float tot = red[0] + red[1] + red[2] + red[3];
    float inv = 1.f / fmaxf(sqrtf(tot), 1e-12f);
    float sg = 1.f / (1.f + __expf(-sc[w]));
    float m = inv * sg;
    for (int h = tid; h < 1024; h += 256) kern[w * 1024 + h] = mw[w * 1024 + h] * m;
}

// ---------------- coeffs = xc @ kern^T  (16384 x 8) ----------------
__global__ __launch_bounds__(256) void k_coeffs(const float* __restrict__ x,
                                                const float* __restrict__ kern,
                                                float* __restrict__ coeffs) {
    __shared__ float kl[8 * 1024];
    int tid = threadIdx.x;
    for (int i = tid; i < 8192; i += 256) kl[i] = kern[i];
    __syncthreads();
    int wid = tid >> 6, lane = tid & 63;
    long row = (long)blockIdx.x * 4 + wid;
    float acc[8] = {0, 0, 0, 0, 0, 0, 0, 0};
    const float* xr = x + row * 1024;
    for (int i = 0; i < 16; i++) {
        float xv = xr[lane + i * 64];
#pragma unroll
        for (int w = 0; w < 8; w++) acc[w] += xv * kl[w * 1024 + lane + i * 64];
    }
#pragma unroll
    for (int xm = 1; xm < 64; xm <<= 1) {
#pragma unroll
        for (int w = 0; w < 8; w++) acc[w] += __shfl_xor(acc[w], xm);
    }
    if (lane == 0) {
#pragma unroll
        for (int w = 0; w < 8; w++) coeffs[row * 8 + w] = acc[w];
    }
}

// ---------------- hid = LN(coeffs@w1 + b1); g = gelu(hid) (bf16) ----------------
__global__ __launch_bounds__(256) void k_mix1(const float* __restrict__ coeffs,
                                              const float* __restrict__ w1,
                                              const float* __restrict__ b1,
                                              const float* __restrict__ lng,
                                              const float* __restrict__ lnb,
                                              bf16* __restrict__ g) {
    long row = blockIdx.x;
    int tid = threadIdx.x;
    int wid = tid >> 6, lane = tid & 63;
    __shared__ float cf[8];
    __shared__ float red1[4], red2[4];
    if (tid < 8) cf[tid] = coeffs[row * 8 + tid];
    __syncthreads();
    float h0[2];
#pragma unroll
    for (int t = 0; t < 2; t++) {
        int j = tid + t * 256;
        float a = b1[j];
#pragma unroll
        for (int w = 0; w < 8; w++) a += cf[w] * w1[w * 512 + j];
        h0[t] = a;
    }
    float s1 = h0[0] + h0[1];
    float s2 = h0[0] * h0[0] + h0[1] * h0[1];
#pragma unroll
    for (int xm = 1; xm < 64; xm <<= 1) {
        s1 += __shfl_xor(s1, xm);
        s2 += __shfl_xor(s2, xm);
    }
    if (lane == 0) { red1[wid] = s1; red2[wid] = s2; }
    __syncthreads();
    s1 = red1[0] + red1[1] + red1[2] + red1[3];
    s2 = red2[0] + red2[1] + red2[2] + red2[3];
    float mean = s1 * (1.f / 512.f);
    float var = s2 * (1.f / 512.f) - mean * mean;
    float inv = rsqrtf(var + 1e-5f);
#pragma unroll
    for (int t = 0; t < 2; t++) {
        int j = tid + t * 256;
        float xn = (h0[t] - mean) * inv * lng[j] + lnb[j];
        float ge = 0.5f * xn * (1.f + erff(xn * 0.70710678118654752f));
        g[row * 512 + j] = (bf16)ge;
    }
}

// ---------------- weight transpose + bf16 convert: wt[n][k] = w[k][n] ----------------
__global__ void k_wtrans(const float* __restrict__ w, bf16* __restrict__ wt, int K, int N) {
    long idx = (long)blockIdx.x * 256 + threadIdx.x;
    if (idx < (long)K * N) {
        int kk = (int)(idx / N);
        int n = (int)(idx % N);
        wt[(long)n * K + kk] = (bf16)w[idx];
    }
}

// ---------------- GEMM: C = scale * (A @ Bt^T) (+ bias), bf16 MFMA ----------------
enum { EPI_BF16 = 0, EPI_BF16_BIAS = 1, EPI_F32_BIAS = 2, EPI_VT = 3, EPI_F32 = 4 };

template <int EPI>
__global__ __launch_bounds__(256) void k_gemm(const bf16* __restrict__ A,
                                              const bf16* __restrict__ Bt,
                                              const float* __restrict__ bias,
                                              void* __restrict__ Cout,
                                              int M, int N, int K,
                                              int lda, int ldb, int ldc, float scale) {
    __shared__ bf16 As[128][40];
    __shared__ bf16 Bs[128][40];
    int tid = threadIdx.x;
    int wid = tid >> 6, lane = tid & 63;
    int wr = wid >> 1, wc = wid & 1;
    long m0 = (long)blockIdx.y * 128, n0 = (long)blockIdx.x * 128;
    f32x4 acc[4][4] = {};
    const int lr = lane & 15, ko = (lane >> 4) << 3;
    const int arow = tid >> 2, acol = (tid & 3) << 3;
    for (int k0 = 0; k0 < K; k0 += 32) {
        *(ushort8_t*)&As[arow][acol] = *(const ushort8_t*)&A[(m0 + arow) * lda + k0 + acol];
        *(ushort8_t*)&As[arow + 64][acol] = *(const ushort8_t*)&A[(m0 + arow + 64) * lda + k0 + acol];
        *(ushort8_t*)&Bs[arow][acol] = *(const ushort8_t*)&Bt[(n0 + arow) * ldb + k0 + acol];
        *(ushort8_t*)&Bs[arow + 64][acol] = *(const ushort8_t*)&Bt[(n0 + arow + 64) * ldb + k0 + acol];
        __syncthreads();
        bf16x8 af[4], bfr[4];
#pragma unroll
        for (int i = 0; i < 4; i++) af[i] = *(const bf16x8*)&As[wr * 64 + i * 16 + lr][ko];
#pragma unroll
        for (int i = 0; i < 4; i++) bfr[i] = *(const bf16x8*)&Bs[wc * 64 + i * 16 + lr][ko];
#pragma unroll
        for (int i = 0; i < 4; i++) {
#pragma unroll
            for (int j = 0; j < 4; j++)
                acc[i][j] = __builtin_amdgcn_mfma_f32_16x16x32_bf16(af[i], bfr[j], acc[i][j], 0, 0, 0);
        }
        __syncthreads();
    }
    const int r0 = (lane >> 4) << 2;
#pragma unroll
    for (int i = 0; i < 4; i++) {
#pragma unroll
        for (int j = 0; j < 4; j++) {
#pragma unroll
            for (int e = 0; e < 4; e++) {
                long m = m0 + wr * 64 + i * 16 + r0 + e;
                long n = n0 + wc * 64 + j * 16 + lr;
                float v = acc[i][j][e] * scale;
                if constexpr (EPI == EPI_BF16_BIAS || EPI == EPI_F32_BIAS) v += bias[n];
                if constexpr (EPI == EPI_F32_BIAS || EPI == EPI_F32) {
                    ((float*)Cout)[m * ldc + n] = v;
                } else if constexpr (EPI == EPI_VT) {
                    long c = m >> 10, s = m & 1023, h = n >> 8, d = n & 255;
                    ((bf16*)Cout)[(((c << 2) + h) << 18) + (d << 10) + s] = (bf16)v;
                } else {
                    ((bf16*)Cout)[m * ldc + n] = (bf16)v;
                }
            }
        }
    }
}

// ---------------- flash attention per (chunk, head, 64 q-rows) ----------------
__global__ __launch_bounds__(256) void k_attn(const bf16* __restrict__ q,
                                              const bf16* __restrict__ k,
                                              const bf16* __restrict__ vt,
                                              bf16* __restrict__ ao) {
    __shared__ bf16 Ks[64][264];
    __shared__ bf16 Vs[256][72];
    __shared__ bf16 Ps[4][16][72];
    int tid = threadIdx.x;
    int wid = tid >> 6, lane = tid & 63;
    int c = blockIdx.z, h = blockIdx.y, q0 = blockIdx.x * 64;
    const int lr = lane & 15, ko = (lane >> 4) << 3;
    long qrow = (long)c * 1024 + q0 + wid * 16 + lr;
    bf16x8 qf[8];
#pragma unroll
    for (int kk = 0; kk < 8; kk++)
        qf[kk] = *(const bf16x8*)&q[qrow * 1024 + h * 256 + kk * 32 + ko];
    f32x4 oacc[16] = {};
    float m_run[4] = {-1e30f, -1e30f, -1e30f, -1e30f};
    float l_run[4] = {0.f, 0.f, 0.f, 0.f};
    for (int kb = 0; kb < 1024; kb += 64) {
        {
            int r = tid >> 5, cc = (tid & 31) << 3;
#pragma unroll
            for (int p = 0; p < 8; p++)
                *(ushort8_t*)&Ks[p * 8 + r][cc] =
                    *(const ushort8_t*)&k[((long)c * 1024 + kb + p * 8 + r) * 1024 + h * 256 + cc];
            int d = tid >> 3, ss = (tid & 7) << 3;
#pragma unroll
            for (int p = 0; p < 8; p++)
                *(ushort8_t*)&Vs[p * 32 + d][ss] =
                    *(const ushort8_t*)&vt[(((long)(c * 4 + h)) << 18) + (long)(p * 32 + d) * 1024 + kb + ss];
        }
        __syncthreads();
        f32x4 s[4] = {};
#pragma unroll
        for (int kk = 0; kk < 8; kk++) {
#pragma unroll
            for (int n = 0; n < 4; n++)
                s[n] = __builtin_amdgcn_mfma_f32_16x16x32_bf16(
                    qf[kk], *(const bf16x8*)&Ks[n * 16 + lr][kk * 32 + ko], s[n], 0, 0, 0);
        }
        float mx[4], al[4], rs[4];
#pragma unroll
        for (int e = 0; e < 4; e++)
            mx[e] = fmaxf(fmaxf(s[0][e], s[1][e]), fmaxf(s[2][e], s[3][e]));
#pragma unroll
        for (int xm = 1; xm < 16; xm <<= 1) {
#pragma unroll
            for (int e = 0; e < 4; e++) mx[e] = fmaxf(mx[e], __shfl_xor(mx[e], xm));
        }
#pragma unroll
        for (int e = 0; e < 4; e++) {
            float mn = fmaxf(m_run[e], mx[e]);
            al[e] = __expf(m_run[e] - mn);
            m_run[e] = mn;
            rs[e] = 0.f;
        }
#pragma unroll
        for (int n = 0; n < 4; n++) {
#pragma unroll
            for (int e = 0; e < 4; e++) {
                float p = __expf(s[n][e] - m_run[e]);
                s[n][e] = p;
                rs[e] += p;
            }
        }
#pragma unroll
        for (int xm = 1; xm < 16; xm <<= 1) {
#pragma unroll
            for (int e = 0; e < 4; e++) rs[e] += __shfl_xor(rs[e], xm);
        }
#pragma unroll
        for (int e = 0; e < 4; e++) l_run[e] = l_run[e] * al[e] + rs[e];
#pragma unroll
        for (int f = 0; f < 16; f++) {
#pragma unroll
            for (int e = 0; e < 4; e++) oacc[f][e] *= al[e];
        }
#pragma unroll
        for (int n = 0; n < 4; n++) {
#pragma unroll
            for (int e = 0; e < 4; e++)
                Ps[wid][(lane >> 4) * 4 + e][n * 16 + lr] = (bf16)s[n][e];
        }
        __syncthreads();
        bf16x8 pf0 = *(const bf16x8*)&Ps[wid][lr][ko];
        bf16x8 pf1 = *(const bf16x8*)&Ps[wid][lr][32 + ko];
#pragma unroll
        for (int n2 = 0; n2 < 16; n2++) {
            oacc[n2] = __builtin_amdgcn_mfma_f32_16x16x32_bf16(
                pf0, *(const bf16x8*)&Vs[n2 * 16 + lr][ko], oacc[n2], 0, 0, 0);
            oacc[n2] = __builtin_amdgcn_mfma_f32_16x16x32_bf16(
                pf1, *(const bf16x8*)&Vs[n2 * 16 + lr][32 + ko], oacc[n2], 0, 0, 0);
        }
        __syncthreads();
    }
#pragma unroll
    for (int n2 = 0; n2 < 16; n2++) {
#pragma unroll
        for (int e = 0; e < 4; e++) {
            long row = (long)c * 1024 + q0 + wid * 16 + (lane >> 4) * 4 + e;
            long col = (long)h * 256 + n2 * 16 + lr;
            ao[row * 1024 + col] = (bf16)(oacc[n2][e] / l_run[e]);
        }
    }
}

// ---------------- t = LN(o + mixed) (bf16) ----------------
__global__ __launch_bounds__(256) void k_outln(const float* __restrict__ o,
                                               const bf16* __restrict__ mixed,
                                               const float* __restrict__ g,
                                               const float* __restrict__ b,
                                               bf16* __restrict__ t) {
    long row = blockIdx.x;
    int tid = threadIdx.x;
    int wid = tid >> 6, lane = tid & 63;
    __shared__ float red1[4], red2[4];
    float x[4];
    const float* orow = o + row * 1024;
    const bf16* mrow = mixed + row * 1024;
#pragma unroll
    for (int i = 0; i < 4; i++) {
        int j = tid * 4 + i;
        x[i] = orow[j] + (float)mrow[j];
    }
    float s1 = x[0] + x[1] + x[2] + x[3];
    float s2 = x[0] * x[0] + x[1] * x[1] + x[2] * x[2] + x[3] * x[3];
#pragma unroll
    for (int xm = 1; xm < 64; xm <<= 1) {
        s1 += __shfl_xor(s1, xm);
        s2 += __shfl_xor(s2, xm);
    }
    if (lane == 0) { red1[wid] = s1; red2[wid] = s2; }
    __syncthreads();
    s1 = red1[0] + red1[1] + red1[2] + red1[3];
    s2 = red2[0] + red2[1] + red2[2] + red2[3];
    float mean = s1 * (1.f / 1024.f);
    float var = s2 * (1.f / 1024.f) - mean * mean;
    float inv = rsqrtf(var + 1e-5f);
#pragma unroll
    for (int i = 0; i < 4; i++) {
        int j = tid * 4 + i;
        t[row * 1024 + j] = (bf16)((x[i] - mean) * inv * g[j] + b[j]);
    }
}

extern "C" void kernel_launch(void* const* d_in, const int* in_sizes, int n_in,
                              void* d_out, int out_size, void* d_ws, size_t ws_size,
                              hipStream_t stream) {
    const float* x   = (const float*)d_in[0];
    const float* mw  = (const float*)d_in[1];
    const float* sc  = (const float*)d_in[2];
    const float* w1  = (const float*)d_in[3];
    const float* b1  = (const float*)d_in[4];
    const float* lng1 = (const float*)d_in[5];
    const float* lnb1 = (const float*)d_in[6];
    const float* w2  = (const float*)d_in[7];
    const float* b2  = (const float*)d_in[8];
    const float* wq  = (const float*)d_in[9];
    const float* wk  = (const float*)d_in[10];
    const float* wv  = (const float*)d_in[11];
    const float* wo  = (const float*)d_in[12];
    const float* lng2 = (const float*)d_in[13];
    const float* lnb2 = (const float*)d_in[14];
    const float* ow  = (const float*)d_in[15];
    const float* ob  = (const float*)d_in[16];

    char* p = (char*)d_ws;
    auto take = [&](size_t bytes) {
        char* r = p;
        p += (bytes + 255) & ~(size_t)255;
        return r;
    };
    const size_t M = 16384;
    float* kern   = (float*)take(8 * 1024 * sizeof(float));
    float* coeffs = (float*)take(M * 8 * sizeof(float));
    bf16* g       = (bf16*)take(M * 512 * 2);
    bf16* mixed   = (bf16*)take(M * 1024 * 2);
    bf16* qb      = (bf16*)take(M * 1024 * 2 * 2);  // q followed by k; reused as o(f32) later
    bf16* kb2     = qb + M * 1024;
    float* o32    = (float*)qb;
    bf16* vtb     = (bf16*)take(M * 1024 * 2);      // v transposed per (chunk,head); reused as t later
    bf16* tb      = vtb;
    bf16* aob     = (bf16*)take(M * 1024 * 2);
    bf16* w2t     = (bf16*)take((size_t)1024 * 512 * 2);
    bf16* wqt     = (bf16*)take((size_t)1024 * 1024 * 2);
    bf16* wkt     = (bf16*)take((size_t)1024 * 1024 * 2);
    bf16* wvt     = (bf16*)take((size_t)1024 * 1024 * 2);
    bf16* wot     = (bf16*)take((size_t)1024 * 1024 * 2);
    bf16* owt     = (bf16*)take((size_t)256 * 1024 * 2);

    k_wavelet<<<8, 256, 0, stream>>>(mw, sc, kern);
    k_coeffs<<<4096, 256, 0, stream>>>(x, kern, coeffs);
    k_mix1<<<16384, 256, 0, stream>>>(coeffs, w1, b1, lng1, lnb1, g);

    k_wtrans<<<(512 * 1024) / 256, 256, 0, stream>>>(w2, w2t, 512, 1024);
    k_wtrans<<<(1024 * 1024) / 256, 256, 0, stream>>>(wq, wqt, 1024, 1024);
    k_wtrans<<<(1024 * 1024) / 256, 256, 0, stream>>>(wk, wkt, 1024, 1024);
    k_wtrans<<<(1024 * 1024) / 256, 256, 0, stream>>>(wv, wvt, 1024, 1024);
    k_wtrans<<<(1024 * 1024) / 256, 256, 0, stream>>>(wo, wot, 1024, 1024);
    k_wtrans<<<(1024 * 256) / 256, 256, 0, stream>>>(ow, owt, 1024, 256);

    // mixed = gelu(hid) @ w2 + b2
    k_gemm<EPI_BF16_BIAS><<<dim3(8, 128), 256, 0, stream>>>(
        g, w2t, b2, mixed, 16384, 1024, 512, 512, 512, 1024, 1.f);
    // q (scaled by hd^-0.5), k, v(transposed layout)
    k_gemm<EPI_BF16><<<dim3(8, 128), 256, 0, stream>>>(
        mixed, wqt, nullptr, qb, 16384, 1024, 1024, 1024, 1024, 1024, 0.0625f);
    k_gemm<EPI_BF16><<<dim3(8, 128), 256, 0, stream>>>(
        mixed, wkt, nullptr, kb2, 16384, 1024, 1024, 1024, 1024, 1024, 1.f);
    k_gemm<EPI_VT><<<dim3(8, 128), 256, 0, stream>>>(
        mixed, wvt, nullptr, vtb, 16384, 1024, 1024, 1024, 1024, 1024, 1.f);
    // attention
    k_attn<<<dim3(16, 4, 16), 256, 0, stream>>>(qb, kb2, vtb, aob);
    // o = ao @ wo (fp32, overwrites q+k region)
    k_gemm<EPI_F32><<<dim3(8, 128), 256, 0, stream>>>(
        aob, wot, nullptr, o32, 16384, 1024, 1024, 1024, 1024, 1024, 1.f);
    // t = LN(o + mixed) (overwrites vt region)
    k_outln<<<16384, 256, 0, stream>>>(o32, mixed, lng2, lnb2, tb);
    // y = t @ out_w + out_b
    k_gemm<EPI_F32_BIAS><<<dim3(2, 128), 256, 0, stream>>>(
        tb, owt, ob, d_out, 16384, 256, 1024, 1024, 1024, 256, 1.f);
}

// Round 2
// 567.066 us; speedup vs baseline: 1.0264x; 1.0264x over previous
//
#include <hip/hip_runtime.h>
#include <hip/hip_bf16.h>

typedef __bf16 bf16;
typedef __bf16 bf16x8 __attribute__((ext_vector_type(8)));
typedef float f32x4 __attribute__((ext_vector_type(4)));
typedef unsigned short ushort8_t __attribute__((ext_vector_type(8)));

#define GLOAD_LDS16(g, l)                                                      \
    __builtin_amdgcn_global_load_lds(                                          \
        (const __attribute__((address_space(1))) void*)(g),                    \
        (__attribute__((address_space(3))) void*)(l), 16, 0, 0)

// Problem constants
// B=4, S=4096, H=1024, G=256, W=8, CHUNK=1024, NUM_HEADS=4, hd=256
// M = B*S = 16384 rows, NC = 16 chunks

// ---------------- wavelet kernel normalization ----------------
__global__ __launch_bounds__(256) void k_wavelet(const float* __restrict__ mw,
                                                 const float* __restrict__ sc,
                                                 float* __restrict__ kern) {
    int w = blockIdx.x;
    int tid = threadIdx.x;
    float s = 0.f;
    for (int h = tid; h < 1024; h += 256) { float v = mw[w * 1024 + h]; s += v * v; }
#pragma unroll
    for (int xm = 1; xm < 64; xm <<= 1) s += __shfl_xor(s, xm);
    __shared__ float red[4];
    if ((tid & 63) == 0) red[tid >> 6] = s;
    __syncthreads();
    float tot = red[0] + red[1] + red[2] + red[3];
    float inv = 1.f / fmaxf(sqrtf(tot), 1e-12f);
    float sg = 1.f / (1.f + __expf(-sc[w]));
    float m = inv * sg;
    for (int h = tid; h < 1024; h += 256) kern[w * 1024 + h] = mw[w * 1024 + h] * m;
}

// ---------------- coeffs = xc @ kern^T  (16384 x 8) ----------------
__global__ __launch_bounds__(256) void k_coeffs(const float* __restrict__ x,
                                                const float* __restrict__ kern,
                                                float* __restrict__ coeffs) {
    __shared__ float kl[8 * 1024];
    int tid = threadIdx.x;
    for (int i = tid; i < 8192; i += 256) kl[i] = kern[i];
    __syncthreads();
    int wid = tid >> 6, lane = tid & 63;
    long row = (long)blockIdx.x * 4 + wid;
    float acc[8] = {0, 0, 0, 0, 0, 0, 0, 0};
    const float* xr = x + row * 1024;
    for (int i = 0; i < 16; i++) {
        float xv = xr[lane + i * 64];
#pragma unroll
        for (int w = 0; w < 8; w++) acc[w] += xv * kl[w * 1024 + lane + i * 64];
    }
#pragma unroll
    for (int xm = 1; xm < 64; xm <<= 1) {
#pragma unroll
        for (int w = 0; w < 8; w++) acc[w] += __shfl_xor(acc[w], xm);
    }
    if (lane == 0) {
#pragma unroll
        for (int w = 0; w < 8; w++) coeffs[row * 8 + w] = acc[w];
    }
}

// ---------------- hid = LN(coeffs@w1 + b1); g = gelu(hid) (bf16) ----------------
__global__ __launch_bounds__(256) void k_mix1(const float* __restrict__ coeffs,
                                              const float* __restrict__ w1,
                                              const float* __restrict__ b1,
                                              const float* __restrict__ lng,
                                              const float* __restrict__ lnb,
                                              bf16* __restrict__ g) {
    long row = blockIdx.x;
    int tid = threadIdx.x;
    int wid = tid >> 6, lane = tid & 63;
    __shared__ float cf[8];
    __shared__ float red1[4], red2[4];
    if (tid < 8) cf[tid] = coeffs[row * 8 + tid];
    __syncthreads();
    float h0[2];
#pragma unroll
    for (int t = 0; t < 2; t++) {
        int j = tid + t * 256;
        float a = b1[j];
#pragma unroll
        for (int w = 0; w < 8; w++) a += cf[w] * w1[w * 512 + j];
        h0[t] = a;
    }
    float s1 = h0[0] + h0[1];
    float s2 = h0[0] * h0[0] + h0[1] * h0[1];
#pragma unroll
    for (int xm = 1; xm < 64; xm <<= 1) {
        s1 += __shfl_xor(s1, xm);
        s2 += __shfl_xor(s2, xm);
    }
    if (lane == 0) { red1[wid] = s1; red2[wid] = s2; }
    __syncthreads();
    s1 = red1[0] + red1[1] + red1[2] + red1[3];
    s2 = red2[0] + red2[1] + red2[2] + red2[3];
    float mean = s1 * (1.f / 512.f);
    float var = s2 * (1.f / 512.f) - mean * mean;
    float inv = rsqrtf(var + 1e-5f);
#pragma unroll
    for (int t = 0; t < 2; t++) {
        int j = tid + t * 256;
        float xn = (h0[t] - mean) * inv * lng[j] + lnb[j];
        float ge = 0.5f * xn * (1.f + erff(xn * 0.70710678118654752f));
        g[row * 512 + j] = (bf16)ge;
    }
}

// ---------------- weight transpose + bf16 convert: wt[n][k] = w[k][n] ----------------
__global__ void k_wtrans(const float* __restrict__ w, bf16* __restrict__ wt, int K, int N) {
    long idx = (long)blockIdx.x * 256 + threadIdx.x;
    if (idx < (long)K * N) {
        int kk = (int)(idx / N);
        int n = (int)(idx % N);
        wt[(long)n * K + kk] = (bf16)w[idx];
    }
}

// ---------------- GEMM: C = scale * (A @ Bt^T) (+ bias), bf16 MFMA ----------------
// m97 structure: linear [128][32] LDS tiles staged via global_load_lds width=16,
// ds_read_b128 fragments, 16 MFMA per K-step, 2 barriers per K-step.
enum { EPI_BF16 = 0, EPI_BF16_BIAS = 1, EPI_F32_BIAS = 2, EPI_VT = 3, EPI_F32 = 4 };

template <int EPI>
__global__ __launch_bounds__(256) void k_gemm(const bf16* __restrict__ A,
                                              const bf16* __restrict__ Bt,
                                              const float* __restrict__ bias,
                                              void* __restrict__ Cout,
                                              int M, int N, int K,
                                              int lda, int ldb, int ldc, float scale) {
    __shared__ bf16 As[128 * 32];
    __shared__ bf16 Bs[128 * 32];
    int tid = threadIdx.x;
    int wid = tid >> 6, lane = tid & 63;
    int wr = wid >> 1, wc = wid & 1;
    long m0 = (long)blockIdx.y * 128, n0 = (long)blockIdx.x * 128;
    f32x4 acc[4][4] = {};
    const int lr = lane & 15, ko = (lane >> 4) << 3;

    // staging geometry: wave `wid` fills LDS chunks 2*wid, 2*wid+1 (1 KiB each).
    // chunk c holds tile rows c*16 .. c*16+15; lane l -> row c*16 + (l>>2),
    // cols (l&3)*8 .. +7.  LDS dest = chunk base + lane*16 (HW-enforced linear).
    const int srow = wid * 32 + (lane >> 2);
    const int scol = (lane & 3) << 3;
    const bf16* a0 = A + (m0 + srow) * lda + scol;
    const bf16* a1 = A + (m0 + srow + 16) * lda + scol;
    const bf16* b0 = Bt + (n0 + srow) * ldb + scol;
    const bf16* b1 = Bt + (n0 + srow + 16) * ldb + scol;
    bf16* la0 = As + wid * 1024;   // elements; = byte base (2*wid)*1024
    bf16* la1 = As + wid * 1024 + 512;
    bf16* lb0 = Bs + wid * 1024;
    bf16* lb1 = Bs + wid * 1024 + 512;

    for (int k0 = 0; k0 < K; k0 += 32) {
        GLOAD_LDS16(a0 + k0, la0);
        GLOAD_LDS16(a1 + k0, la1);
        GLOAD_LDS16(b0 + k0, lb0);
        GLOAD_LDS16(b1 + k0, lb1);
        __syncthreads();
        bf16x8 af[4], bfr[4];
#pragma unroll
        for (int i = 0; i < 4; i++)
            af[i] = *(const bf16x8*)&As[(wr * 64 + i * 16 + lr) * 32 + ko];
#pragma unroll
        for (int i = 0; i < 4; i++)
            bfr[i] = *(const bf16x8*)&Bs[(wc * 64 + i * 16 + lr) * 32 + ko];
#pragma unroll
        for (int i = 0; i < 4; i++) {
#pragma unroll
            for (int j = 0; j < 4; j++)
                acc[i][j] = __builtin_amdgcn_mfma_f32_16x16x32_bf16(af[i], bfr[j], acc[i][j], 0, 0, 0);
        }
        __syncthreads();
    }
    const int r0 = (lane >> 4) << 2;
#pragma unroll
    for (int i = 0; i < 4; i++) {
#pragma unroll
        for (int j = 0; j < 4; j++) {
#pragma unroll
            for (int e = 0; e < 4; e++) {
                long m = m0 + wr * 64 + i * 16 + r0 + e;
                long n = n0 + wc * 64 + j * 16 + lr;
                float v = acc[i][j][e] * scale;
                if constexpr (EPI == EPI_BF16_BIAS || EPI == EPI_F32_BIAS) v += bias[n];
                if constexpr (EPI == EPI_F32_BIAS || EPI == EPI_F32) {
                    ((float*)Cout)[m * ldc + n] = v;
                } else if constexpr (EPI == EPI_VT) {
                    long c = m >> 10, s = m & 1023, h = n >> 8, d = n & 255;
                    ((bf16*)Cout)[(((c << 2) + h) << 18) + (d << 10) + s] = (bf16)v;
                } else {
                    ((bf16*)Cout)[m * ldc + n] = (bf16)v;
                }
            }
        }
    }
}

// ---------------- flash attention per (chunk, head, 64 q-rows) ----------------
__global__ __launch_bounds__(256) void k_attn(const bf16* __restrict__ q,
                                              const bf16* __restrict__ k,
                                              const bf16* __restrict__ vt,
                                              bf16* __restrict__ ao) {
    __shared__ bf16 Ks[64][264];
    __shared__ bf16 Vs[256][72];
    __shared__ bf16 Ps[4][16][72];
    int tid = threadIdx.x;
    int wid = tid >> 6, lane = tid & 63;
    int c = blockIdx.z, h = blockIdx.y, q0 = blockIdx.x * 64;
    const int lr = lane & 15, ko = (lane >> 4) << 3;
    long qrow = (long)c * 1024 + q0 + wid * 16 + lr;
    bf16x8 qf[8];
#pragma unroll
    for (int kk = 0; kk < 8; kk++)
        qf[kk] = *(const bf16x8*)&q[qrow * 1024 + h * 256 + kk * 32 + ko];
    f32x4 oacc[16] = {};
    float m_run[4] = {-1e30f, -1e30f, -1e30f, -1e30f};
    float l_run[4] = {0.f, 0.f, 0.f, 0.f};
    for (int kb = 0; kb < 1024; kb += 64) {
        {
            int r = tid >> 5, cc = (tid & 31) << 3;
#pragma unroll
            for (int p = 0; p < 8; p++)
                *(ushort8_t*)&Ks[p * 8 + r][cc] =
                    *(const ushort8_t*)&k[((long)c * 1024 + kb + p * 8 + r) * 1024 + h * 256 + cc];
            int d = tid >> 3, ss = (tid & 7) << 3;
#pragma unroll
            for (int p = 0; p < 8; p++)
                *(ushort8_t*)&Vs[p * 32 + d][ss] =
                    *(const ushort8_t*)&vt[(((long)(c * 4 + h)) << 18) + (long)(p * 32 + d) * 1024 + kb + ss];
        }
        __syncthreads();
        f32x4 s[4] = {};
#pragma unroll
        for (int kk = 0; kk < 8; kk++) {
#pragma unroll
            for (int n = 0; n < 4; n++)
                s[n] = __builtin_amdgcn_mfma_f32_16x16x32_bf16(
                    qf[kk], *(const bf16x8*)&Ks[n * 16 + lr][kk * 32 + ko], s[n], 0, 0, 0);
        }
        float mx[4], al[4], rs[4];
#pragma unroll
        for (int e = 0; e < 4; e++)
            mx[e] = fmaxf(fmaxf(s[0][e], s[1][e]), fmaxf(s[2][e], s[3][e]));
#pragma unroll
        for (int xm = 1; xm < 16; xm <<= 1) {
#pragma unroll
            for (int e = 0; e < 4; e++) mx[e] = fmaxf(mx[e], __shfl_xor(mx[e], xm));
        }
#pragma unroll
        for (int e = 0; e < 4; e++) {
            float mn = fmaxf(m_run[e], mx[e]);
            al[e] = __expf(m_run[e] - mn);
            m_run[e] = mn;
            rs[e] = 0.f;
        }
#pragma unroll
        for (int n = 0; n < 4; n++) {
#pragma unroll
            for (int e = 0; e < 4; e++) {
                float p = __expf(s[n][e] - m_run[e]);
                s[n][e] = p;
                rs[e] += p;
            }
        }
#pragma unroll
        for (int xm = 1; xm < 16; xm <<= 1) {
#pragma unroll
            for (int e = 0; e < 4; e++) rs[e] += __shfl_xor(rs[e], xm);
        }
#pragma unroll
        for (int e = 0; e < 4; e++) l_run[e] = l_run[e] * al[e] + rs[e];
#pragma unroll
        for (int f = 0; f < 16; f++) {
#pragma unroll
            for (int e = 0; e < 4; e++) oacc[f][e] *= al[e];
        }
#pragma unroll
        for (int n = 0; n < 4; n++) {
#pragma unroll
            for (int e = 0; e < 4; e++)
                Ps[wid][(lane >> 4) * 4 + e][n * 16 + lr] = (bf16)s[n][e];
        }
        __syncthreads();
        bf16x8 pf0 = *(const bf16x8*)&Ps[wid][lr][ko];
        bf16x8 pf1 = *(const bf16x8*)&Ps[wid][lr][32 + ko];
#pragma unroll
        for (int n2 = 0; n2 < 16; n2++) {
            oacc[n2] = __builtin_amdgcn_mfma_f32_16x16x32_bf16(
                pf0, *(const bf16x8*)&Vs[n2 * 16 + lr][ko], oacc[n2], 0, 0, 0);
            oacc[n2] = __builtin_amdgcn_mfma_f32_16x16x32_bf16(
                pf1, *(const bf16x8*)&Vs[n2 * 16 + lr][32 + ko], oacc[n2], 0, 0, 0);
        }
        __syncthreads();
    }
#pragma unroll
    for (int n2 = 0; n2 < 16; n2++) {
#pragma unroll
        for (int e = 0; e < 4; e++) {
            long row = (long)c * 1024 + q0 + wid * 16 + (lane >> 4) * 4 + e;
            long col = (long)h * 256 + n2 * 16 + lr;
            ao[row * 1024 + col] = (bf16)(oacc[n2][e] / l_run[e]);
        }
    }
}

// ---------------- t = LN(o + mixed) (bf16) ----------------
__global__ __launch_bounds__(256) void k_outln(const float* __restrict__ o,
                                               const bf16* __restrict__ mixed,
                                               const float* __restrict__ g,
                                               const float* __restrict__ b,
                                               bf16* __restrict__ t) {
    long row = blockIdx.x;
    int tid = threadIdx.x;
    int wid = tid >> 6, lane = tid & 63;
    __shared__ float red1[4], red2[4];
    float x[4];
    const float* orow = o + row * 1024;
    const bf16* mrow = mixed + row * 1024;
#pragma unroll
    for (int i = 0; i < 4; i++) {
        int j = tid * 4 + i;
        x[i] = orow[j] + (float)mrow[j];
    }
    float s1 = x[0] + x[1] + x[2] + x[3];
    float s2 = x[0] * x[0] + x[1] * x[1] + x[2] * x[2] + x[3] * x[3];
#pragma unroll
    for (int xm = 1; xm < 64; xm <<= 1) {
        s1 += __shfl_xor(s1, xm);
        s2 += __shfl_xor(s2, xm);
    }
    if (lane == 0) { red1[wid] = s1; red2[wid] = s2; }
    __syncthreads();
    s1 = red1[0] + red1[1] + red1[2] + red1[3];
    s2 = red2[0] + red2[1] + red2[2] + red2[3];
    float mean = s1 * (1.f / 1024.f);
    float var = s2 * (1.f / 1024.f) - mean * mean;
    float inv = rsqrtf(var + 1e-5f);
#pragma unroll
    for (int i = 0; i < 4; i++) {
        int j = tid * 4 + i;
        t[row * 1024 + j] = (bf16)((x[i] - mean) * inv * g[j] + b[j]);
    }
}

extern "C" void kernel_launch(void* const* d_in, const int* in_sizes, int n_in,
                              void* d_out, int out_size, void* d_ws, size_t ws_size,
                              hipStream_t stream) {
    const float* x   = (const float*)d_in[0];
    const float* mw  = (const float*)d_in[1];
    const float* sc  = (const float*)d_in[2];
    const float* w1  = (const float*)d_in[3];
    const float* b1  = (const float*)d_in[4];
    const float* lng1 = (const float*)d_in[5];
    const float* lnb1 = (const float*)d_in[6];
    const float* w2  = (const float*)d_in[7];
    const float* b2  = (const float*)d_in[8];
    const float* wq  = (const float*)d_in[9];
    const float* wk  = (const float*)d_in[10];
    const float* wv  = (const float*)d_in[11];
    const float* wo  = (const float*)d_in[12];
    const float* lng2 = (const float*)d_in[13];
    const float* lnb2 = (const float*)d_in[14];
    const float* ow  = (const float*)d_in[15];
    const float* ob  = (const float*)d_in[16];

    char* p = (char*)d_ws;
    auto take = [&](size_t bytes) {
        char* r = p;
        p += (bytes + 255) & ~(size_t)255;
        return r;
    };
    const size_t M = 16384;
    float* kern   = (float*)take(8 * 1024 * sizeof(float));
    float* coeffs = (float*)take(M * 8 * sizeof(float));
    bf16* g       = (bf16*)take(M * 512 * 2);
    bf16* mixed   = (bf16*)take(M * 1024 * 2);
    bf16* qb      = (bf16*)take(M * 1024 * 2 * 2);  // q followed by k; reused as o(f32) later
    bf16* kb2     = qb + M * 1024;
    float* o32    = (float*)qb;
    bf16* vtb     = (bf16*)take(M * 1024 * 2);      // v transposed per (chunk,head); reused as t later
    bf16* tb      = vtb;
    bf16* aob     = (bf16*)take(M * 1024 * 2);
    bf16* w2t     = (bf16*)take((size_t)1024 * 512 * 2);
    bf16* wqt     = (bf16*)take((size_t)1024 * 1024 * 2);
    bf16* wkt     = (bf16*)take((size_t)1024 * 1024 * 2);
    bf16* wvt     = (bf16*)take((size_t)1024 * 1024 * 2);
    bf16* wot     = (bf16*)take((size_t)1024 * 1024 * 2);
    bf16* owt     = (bf16*)take((size_t)256 * 1024 * 2);

    k_wavelet<<<8, 256, 0, stream>>>(mw, sc, kern);
    k_coeffs<<<4096, 256, 0, stream>>>(x, kern, coeffs);
    k_mix1<<<16384, 256, 0, stream>>>(coeffs, w1, b1, lng1, lnb1, g);

    k_wtrans<<<(512 * 1024) / 256, 256, 0, stream>>>(w2, w2t, 512, 1024);
    k_wtrans<<<(1024 * 1024) / 256, 256, 0, stream>>>(wq, wqt, 1024, 1024);
    k_wtrans<<<(1024 * 1024) / 256, 256, 0, stream>>>(wk, wkt, 1024, 1024);
    k_wtrans<<<(1024 * 1024) / 256, 256, 0, stream>>>(wv, wvt, 1024, 1024);
    k_wtrans<<<(1024 * 1024) / 256, 256, 0, stream>>>(wo, wot, 1024, 1024);
    k_wtrans<<<(1024 * 256) / 256, 256, 0, stream>>>(ow, owt, 1024, 256);

    // mixed = gelu(hid) @ w2 + b2
    k_gemm<EPI_BF16_BIAS><<<dim3(8, 128), 256, 0, stream>>>(
        g, w2t, b2, mixed, 16384, 1024, 512, 512, 512, 1024, 1.f);
    // q (scaled by hd^-0.5), k, v(transposed layout)
    k_gemm<EPI_BF16><<<dim3(8, 128), 256, 0, stream>>>(
        mixed, wqt, nullptr, qb, 16384, 1024, 1024, 1024, 1024, 1024, 0.0625f);
    k_gemm<EPI_BF16><<<dim3(8, 128), 256, 0, stream>>>(
        mixed, wkt, nullptr, kb2, 16384, 1024, 1024, 1024, 1024, 1024, 1.f);
    k_gemm<EPI_VT><<<dim3(8, 128), 256, 0, stream>>>(
        mixed, wvt, nullptr, vtb, 16384, 1024, 1024, 1024, 1024, 1024, 1.f);
    // attention
    k_attn<<<dim3(16, 4, 16), 256, 0, stream>>>(qb, kb2, vtb, aob);
    // o = ao @ wo (fp32, overwrites q+k region)
    k_gemm<EPI_F32><<<dim3(8, 128), 256, 0, stream>>>(
        aob, wot, nullptr, o32, 16384, 1024, 1024, 1024, 1024, 1024, 1.f);
    // t = LN(o + mixed) (overwrites vt region)
    k_outln<<<16384, 256, 0, stream>>>(o32, mixed, lng2, lnb2, tb);
    // y = t @ out_w + out_b
    k_gemm<EPI_F32_BIAS><<<dim3(2, 128), 256, 0, stream>>>(
        tb, owt, ob, d_out, 16384, 256, 1024, 1024, 1024, 256, 1.f);
}

// Round 3
// 510.818 us; speedup vs baseline: 1.1395x; 1.1101x over previous
//
#include <hip/hip_runtime.h>
#include <hip/hip_bf16.h>

typedef __bf16 bf16;
typedef __bf16 bf16x8 __attribute__((ext_vector_type(8)));
typedef float f32x4 __attribute__((ext_vector_type(4)));
typedef unsigned short ushort8_t __attribute__((ext_vector_type(8)));

#define GLOAD_LDS16(g, l)                                                      \
    __builtin_amdgcn_global_load_lds(                                          \
        (const __attribute__((address_space(1))) void*)(g),                    \
        (__attribute__((address_space(3))) void*)(l), 16, 0, 0)

// Problem constants
// B=4, S=4096, H=1024, G=256, W=8, CHUNK=1024, NUM_HEADS=4, hd=256
// M = B*S = 16384 rows, NC = 16 chunks

// ---------------- wavelet kernel normalization ----------------
__global__ __launch_bounds__(256) void k_wavelet(const float* __restrict__ mw,
                                                 const float* __restrict__ sc,
                                                 float* __restrict__ kern) {
    int w = blockIdx.x;
    int tid = threadIdx.x;
    float s = 0.f;
    for (int h = tid; h < 1024; h += 256) { float v = mw[w * 1024 + h]; s += v * v; }
#pragma unroll
    for (int xm = 1; xm < 64; xm <<= 1) s += __shfl_xor(s, xm);
    __shared__ float red[4];
    if ((tid & 63) == 0) red[tid >> 6] = s;
    __syncthreads();
    float tot = red[0] + red[1] + red[2] + red[3];
    float inv = 1.f / fmaxf(sqrtf(tot), 1e-12f);
    float sg = 1.f / (1.f + __expf(-sc[w]));
    float m = inv * sg;
    for (int h = tid; h < 1024; h += 256) kern[w * 1024 + h] = mw[w * 1024 + h] * m;
}

// ---------------- coeffs = xc @ kern^T  (16384 x 8) ----------------
__global__ __launch_bounds__(256) void k_coeffs(const float* __restrict__ x,
                                                const float* __restrict__ kern,
                                                float* __restrict__ coeffs) {
    __shared__ float kl[8 * 1024];
    int tid = threadIdx.x;
    for (int i = tid; i < 8192; i += 256) kl[i] = kern[i];
    __syncthreads();
    int wid = tid >> 6, lane = tid & 63;
    long row = (long)blockIdx.x * 4 + wid;
    float acc[8] = {0, 0, 0, 0, 0, 0, 0, 0};
    const float* xr = x + row * 1024;
    for (int i = 0; i < 16; i++) {
        float xv = xr[lane + i * 64];
#pragma unroll
        for (int w = 0; w < 8; w++) acc[w] += xv * kl[w * 1024 + lane + i * 64];
    }
#pragma unroll
    for (int xm = 1; xm < 64; xm <<= 1) {
#pragma unroll
        for (int w = 0; w < 8; w++) acc[w] += __shfl_xor(acc[w], xm);
    }
    if (lane == 0) {
#pragma unroll
        for (int w = 0; w < 8; w++) coeffs[row * 8 + w] = acc[w];
    }
}

// ---------------- hid = LN(coeffs@w1 + b1); g = gelu(hid) (bf16) ----------------
__global__ __launch_bounds__(256) void k_mix1(const float* __restrict__ coeffs,
                                              const float* __restrict__ w1,
                                              const float* __restrict__ b1,
                                              const float* __restrict__ lng,
                                              const float* __restrict__ lnb,
                                              bf16* __restrict__ g) {
    long row = blockIdx.x;
    int tid = threadIdx.x;
    int wid = tid >> 6, lane = tid & 63;
    __shared__ float cf[8];
    __shared__ float red1[4], red2[4];
    if (tid < 8) cf[tid] = coeffs[row * 8 + tid];
    __syncthreads();
    float h0[2];
#pragma unroll
    for (int t = 0; t < 2; t++) {
        int j = tid + t * 256;
        float a = b1[j];
#pragma unroll
        for (int w = 0; w < 8; w++) a += cf[w] * w1[w * 512 + j];
        h0[t] = a;
    }
    float s1 = h0[0] + h0[1];
    float s2 = h0[0] * h0[0] + h0[1] * h0[1];
#pragma unroll
    for (int xm = 1; xm < 64; xm <<= 1) {
        s1 += __shfl_xor(s1, xm);
        s2 += __shfl_xor(s2, xm);
    }
    if (lane == 0) { red1[wid] = s1; red2[wid] = s2; }
    __syncthreads();
    s1 = red1[0] + red1[1] + red1[2] + red1[3];
    s2 = red2[0] + red2[1] + red2[2] + red2[3];
    float mean = s1 * (1.f / 512.f);
    float var = s2 * (1.f / 512.f) - mean * mean;
    float inv = rsqrtf(var + 1e-5f);
#pragma unroll
    for (int t = 0; t < 2; t++) {
        int j = tid + t * 256;
        float xn = (h0[t] - mean) * inv * lng[j] + lnb[j];
        float ge = 0.5f * xn * (1.f + erff(xn * 0.70710678118654752f));
        g[row * 512 + j] = (bf16)ge;
    }
}

// ---------------- weight transpose + bf16 convert: wt[n][k] = w[k][n] ----------------
__global__ void k_wtrans(const float* __restrict__ w, bf16* __restrict__ wt, int K, int N) {
    long idx = (long)blockIdx.x * 256 + threadIdx.x;
    if (idx < (long)K * N) {
        int kk = (int)(idx / N);
        int n = (int)(idx % N);
        wt[(long)n * K + kk] = (bf16)w[idx];
    }
}

enum { EPI_BF16 = 0, EPI_BF16_BIAS = 1, EPI_F32_BIAS = 2, EPI_VT = 3, EPI_F32 = 4 };

// ---------------- GEMM 256x256, 8 waves, BK=64, 2-phase double-buffer ----------------
// T3-minimum recipe: STAGE(next tile, global_load_lds w=16) -> ds_read+MFMA(cur)
// -> one __syncthreads per K-step. Linear LDS (swizzle is null at 2-phase).
template <int EPI>
__global__ __launch_bounds__(512, 2) void k_gemm256(const bf16* __restrict__ A,
                                                    const bf16* __restrict__ Bt,
                                                    const float* __restrict__ bias,
                                                    void* __restrict__ Cout,
                                                    int K, int lda, int ldb, int ldc,
                                                    float scale) {
    __shared__ bf16 As[2 * 256 * 64];
    __shared__ bf16 Bs[2 * 256 * 64];
    int tid = threadIdx.x;
    int wid = tid >> 6, lane = tid & 63;
    int wr = wid >> 2, wc = wid & 3;  // 2 x 4 wave grid; wave owns 128x64 output
    long m0 = (long)blockIdx.y * 256, n0 = (long)blockIdx.x * 256;
    f32x4 acc[8][4] = {};
    const int lr = lane & 15, ko = (lane >> 4) << 3;

    // staging: issue i covers rows i*64 + wid*8 + (lane>>3), cols (lane&7)*8.
    // LDS dest (wave-uniform base, HW adds lane*16B): wid*512 + i*4096 (+buf*16384) elems.
    const int grow = wid * 8 + (lane >> 3);
    const int gcol = (lane & 7) << 3;
    const bf16* aS = A + (m0 + grow) * lda + gcol;
    const bf16* bS = Bt + (n0 + grow) * ldb + gcol;
    bf16* lA = As + wid * 512;
    bf16* lB = Bs + wid * 512;

    const int nt = K >> 6;
    // prologue: tile 0 -> buf 0
#pragma unroll
    for (int i = 0; i < 4; i++) {
        GLOAD_LDS16(aS + (long)(i * 64) * lda, lA + i * 4096);
        GLOAD_LDS16(bS + (long)(i * 64) * ldb, lB + i * 4096);
    }
    __syncthreads();
    int buf = 0;
    for (int t = 0; t < nt; t++) {
        if (t + 1 < nt) {
            const int k0 = (t + 1) << 6;
            const int ob = (buf ^ 1) << 14;
#pragma unroll
            for (int i = 0; i < 4; i++) {
                GLOAD_LDS16(aS + (long)(i * 64) * lda + k0, lA + ob + i * 4096);
                GLOAD_LDS16(bS + (long)(i * 64) * ldb + k0, lB + ob + i * 4096);
            }
        }
        const bf16* At = As + (buf << 14);
        const bf16* Bb = Bs + (buf << 14);
#pragma unroll
        for (int kk = 0; kk < 2; kk++) {
            bf16x8 af[8], bfr[4];
#pragma unroll
            for (int i = 0; i < 8; i++)
                af[i] = *(const bf16x8*)&At[(wr * 128 + i * 16 + lr) * 64 + kk * 32 + ko];
#pragma unroll
            for (int j = 0; j < 4; j++)
                bfr[j] = *(const bf16x8*)&Bb[(wc * 64 + j * 16 + lr) * 64 + kk * 32 + ko];
#pragma unroll
            for (int i = 0; i < 8; i++) {
#pragma unroll
                for (int j = 0; j < 4; j++)
                    acc[i][j] = __builtin_amdgcn_mfma_f32_16x16x32_bf16(af[i], bfr[j], acc[i][j], 0, 0, 0);
            }
        }
        __syncthreads();  // drains vmcnt for next tile + protects buf reuse
        buf ^= 1;
    }
    const int r0 = (lane >> 4) << 2;
#pragma unroll
    for (int i = 0; i < 8; i++) {
#pragma unroll
        for (int j = 0; j < 4; j++) {
#pragma unroll
            for (int e = 0; e < 4; e++) {
                long m = m0 + wr * 128 + i * 16 + r0 + e;
                long n = n0 + wc * 64 + j * 16 + lr;
                float v = acc[i][j][e] * scale;
                if constexpr (EPI == EPI_BF16_BIAS || EPI == EPI_F32_BIAS) v += bias[n];
                if constexpr (EPI == EPI_F32_BIAS || EPI == EPI_F32) {
                    ((float*)Cout)[m * ldc + n] = v;
                } else if constexpr (EPI == EPI_VT) {
                    long c = m >> 10, s = m & 1023, h = n >> 8, d = n & 255;
                    ((bf16*)Cout)[(((c << 2) + h) << 18) + (d << 10) + s] = (bf16)v;
                } else {
                    ((bf16*)Cout)[m * ldc + n] = (bf16)v;
                }
            }
        }
    }
}

// ---------------- GEMM 128x128 (m97 structure) — kept for the N=256 final GEMM ----------------
template <int EPI>
__global__ __launch_bounds__(256) void k_gemm(const bf16* __restrict__ A,
                                              const bf16* __restrict__ Bt,
                                              const float* __restrict__ bias,
                                              void* __restrict__ Cout,
                                              int M, int N, int K,
                                              int lda, int ldb, int ldc, float scale) {
    __shared__ bf16 As[128 * 32];
    __shared__ bf16 Bs[128 * 32];
    int tid = threadIdx.x;
    int wid = tid >> 6, lane = tid & 63;
    int wr = wid >> 1, wc = wid & 1;
    long m0 = (long)blockIdx.y * 128, n0 = (long)blockIdx.x * 128;
    f32x4 acc[4][4] = {};
    const int lr = lane & 15, ko = (lane >> 4) << 3;

    const int srow = wid * 32 + (lane >> 2);
    const int scol = (lane & 3) << 3;
    const bf16* a0 = A + (m0 + srow) * lda + scol;
    const bf16* a1 = A + (m0 + srow + 16) * lda + scol;
    const bf16* b0 = Bt + (n0 + srow) * ldb + scol;
    const bf16* b1 = Bt + (n0 + srow + 16) * ldb + scol;
    bf16* la0 = As + wid * 1024;
    bf16* la1 = As + wid * 1024 + 512;
    bf16* lb0 = Bs + wid * 1024;
    bf16* lb1 = Bs + wid * 1024 + 512;

    for (int k0 = 0; k0 < K; k0 += 32) {
        GLOAD_LDS16(a0 + k0, la0);
        GLOAD_LDS16(a1 + k0, la1);
        GLOAD_LDS16(b0 + k0, lb0);
        GLOAD_LDS16(b1 + k0, lb1);
        __syncthreads();
        bf16x8 af[4], bfr[4];
#pragma unroll
        for (int i = 0; i < 4; i++)
            af[i] = *(const bf16x8*)&As[(wr * 64 + i * 16 + lr) * 32 + ko];
#pragma unroll
        for (int i = 0; i < 4; i++)
            bfr[i] = *(const bf16x8*)&Bs[(wc * 64 + i * 16 + lr) * 32 + ko];
#pragma unroll
        for (int i = 0; i < 4; i++) {
#pragma unroll
            for (int j = 0; j < 4; j++)
                acc[i][j] = __builtin_amdgcn_mfma_f32_16x16x32_bf16(af[i], bfr[j], acc[i][j], 0, 0, 0);
        }
        __syncthreads();
    }
    const int r0 = (lane >> 4) << 2;
#pragma unroll
    for (int i = 0; i < 4; i++) {
#pragma unroll
        for (int j = 0; j < 4; j++) {
#pragma unroll
            for (int e = 0; e < 4; e++) {
                long m = m0 + wr * 64 + i * 16 + r0 + e;
                long n = n0 + wc * 64 + j * 16 + lr;
                float v = acc[i][j][e] * scale;
                if constexpr (EPI == EPI_BF16_BIAS || EPI == EPI_F32_BIAS) v += bias[n];
                if constexpr (EPI == EPI_F32_BIAS || EPI == EPI_F32) {
                    ((float*)Cout)[m * ldc + n] = v;
                } else if constexpr (EPI == EPI_VT) {
                    long c = m >> 10, s = m & 1023, h = n >> 8, d = n & 255;
                    ((bf16*)Cout)[(((c << 2) + h) << 18) + (d << 10) + s] = (bf16)v;
                } else {
                    ((bf16*)Cout)[m * ldc + n] = (bf16)v;
                }
            }
        }
    }
}

// ---------------- flash attention per (chunk, head, 64 q-rows) ----------------
__global__ __launch_bounds__(256) void k_attn(const bf16* __restrict__ q,
                                              const bf16* __restrict__ k,
                                              const bf16* __restrict__ vt,
                                              bf16* __restrict__ ao) {
    __shared__ bf16 Ks[64][264];
    __shared__ bf16 Vs[256][72];
    __shared__ bf16 Ps[4][16][72];
    int tid = threadIdx.x;
    int wid = tid >> 6, lane = tid & 63;
    int c = blockIdx.z, h = blockIdx.y, q0 = blockIdx.x * 64;
    const int lr = lane & 15, ko = (lane >> 4) << 3;
    long qrow = (long)c * 1024 + q0 + wid * 16 + lr;
    bf16x8 qf[8];
#pragma unroll
    for (int kk = 0; kk < 8; kk++)
        qf[kk] = *(const bf16x8*)&q[qrow * 1024 + h * 256 + kk * 32 + ko];
    f32x4 oacc[16] = {};
    float m_run[4] = {-1e30f, -1e30f, -1e30f, -1e30f};
    float l_run[4] = {0.f, 0.f, 0.f, 0.f};
    for (int kb = 0; kb < 1024; kb += 64) {
        {
            int r = tid >> 5, cc = (tid & 31) << 3;
#pragma unroll
            for (int p = 0; p < 8; p++)
                *(ushort8_t*)&Ks[p * 8 + r][cc] =
                    *(const ushort8_t*)&k[((long)c * 1024 + kb + p * 8 + r) * 1024 + h * 256 + cc];
            int d = tid >> 3, ss = (tid & 7) << 3;
#pragma unroll
            for (int p = 0; p < 8; p++)
                *(ushort8_t*)&Vs[p * 32 + d][ss] =
                    *(const ushort8_t*)&vt[(((long)(c * 4 + h)) << 18) + (long)(p * 32 + d) * 1024 + kb + ss];
        }
        __syncthreads();
        f32x4 s[4] = {};
#pragma unroll
        for (int kk = 0; kk < 8; kk++) {
#pragma unroll
            for (int n = 0; n < 4; n++)
                s[n] = __builtin_amdgcn_mfma_f32_16x16x32_bf16(
                    qf[kk], *(const bf16x8*)&Ks[n * 16 + lr][kk * 32 + ko], s[n], 0, 0, 0);
        }
        float mx[4], al[4], rs[4];
#pragma unroll
        for (int e = 0; e < 4; e++)
            mx[e] = fmaxf(fmaxf(s[0][e], s[1][e]), fmaxf(s[2][e], s[3][e]));
#pragma unroll
        for (int xm = 1; xm < 16; xm <<= 1) {
#pragma unroll
            for (int e = 0; e < 4; e++) mx[e] = fmaxf(mx[e], __shfl_xor(mx[e], xm));
        }
#pragma unroll
        for (int e = 0; e < 4; e++) {
            float mn = fmaxf(m_run[e], mx[e]);
            al[e] = __expf(m_run[e] - mn);
            m_run[e] = mn;
            rs[e] = 0.f;
        }
#pragma unroll
        for (int n = 0; n < 4; n++) {
#pragma unroll
            for (int e = 0; e < 4; e++) {
                float p = __expf(s[n][e] - m_run[e]);
                s[n][e] = p;
                rs[e] += p;
            }
        }
#pragma unroll
        for (int xm = 1; xm < 16; xm <<= 1) {
#pragma unroll
            for (int e = 0; e < 4; e++) rs[e] += __shfl_xor(rs[e], xm);
        }
#pragma unroll
        for (int e = 0; e < 4; e++) l_run[e] = l_run[e] * al[e] + rs[e];
#pragma unroll
        for (int f = 0; f < 16; f++) {
#pragma unroll
            for (int e = 0; e < 4; e++) oacc[f][e] *= al[e];
        }
#pragma unroll
        for (int n = 0; n < 4; n++) {
#pragma unroll
            for (int e = 0; e < 4; e++)
                Ps[wid][(lane >> 4) * 4 + e][n * 16 + lr] = (bf16)s[n][e];
        }
        __syncthreads();
        bf16x8 pf0 = *(const bf16x8*)&Ps[wid][lr][ko];
        bf16x8 pf1 = *(const bf16x8*)&Ps[wid][lr][32 + ko];
#pragma unroll
        for (int n2 = 0; n2 < 16; n2++) {
            oacc[n2] = __builtin_amdgcn_mfma_f32_16x16x32_bf16(
                pf0, *(const bf16x8*)&Vs[n2 * 16 + lr][ko], oacc[n2], 0, 0, 0);
            oacc[n2] = __builtin_amdgcn_mfma_f32_16x16x32_bf16(
                pf1, *(const bf16x8*)&Vs[n2 * 16 + lr][32 + ko], oacc[n2], 0, 0, 0);
        }
        __syncthreads();
    }
#pragma unroll
    for (int n2 = 0; n2 < 16; n2++) {
#pragma unroll
        for (int e = 0; e < 4; e++) {
            long row = (long)c * 1024 + q0 + wid * 16 + (lane >> 4) * 4 + e;
            long col = (long)h * 256 + n2 * 16 + lr;
            ao[row * 1024 + col] = (bf16)(oacc[n2][e] / l_run[e]);
        }
    }
}

// ---------------- t = LN(o + mixed) (bf16) ----------------
__global__ __launch_bounds__(256) void k_outln(const float* __restrict__ o,
                                               const bf16* __restrict__ mixed,
                                               const float* __restrict__ g,
                                               const float* __restrict__ b,
                                               bf16* __restrict__ t) {
    long row = blockIdx.x;
    int tid = threadIdx.x;
    int wid = tid >> 6, lane = tid & 63;
    __shared__ float red1[4], red2[4];
    float x[4];
    const float* orow = o + row * 1024;
    const bf16* mrow = mixed + row * 1024;
#pragma unroll
    for (int i = 0; i < 4; i++) {
        int j = tid * 4 + i;
        x[i] = orow[j] + (float)mrow[j];
    }
    float s1 = x[0] + x[1] + x[2] + x[3];
    float s2 = x[0] * x[0] + x[1] * x[1] + x[2] * x[2] + x[3] * x[3];
#pragma unroll
    for (int xm = 1; xm < 64; xm <<= 1) {
        s1 += __shfl_xor(s1, xm);
        s2 += __shfl_xor(s2, xm);
    }
    if (lane == 0) { red1[wid] = s1; red2[wid] = s2; }
    __syncthreads();
    s1 = red1[0] + red1[1] + red1[2] + red1[3];
    s2 = red2[0] + red2[1] + red2[2] + red2[3];
    float mean = s1 * (1.f / 1024.f);
    float var = s2 * (1.f / 1024.f) - mean * mean;
    float inv = rsqrtf(var + 1e-5f);
#pragma unroll
    for (int i = 0; i < 4; i++) {
        int j = tid * 4 + i;
        t[row * 1024 + j] = (bf16)((x[i] - mean) * inv * g[j] + b[j]);
    }
}

extern "C" void kernel_launch(void* const* d_in, const int* in_sizes, int n_in,
                              void* d_out, int out_size, void* d_ws, size_t ws_size,
                              hipStream_t stream) {
    const float* x   = (const float*)d_in[0];
    const float* mw  = (const float*)d_in[1];
    const float* sc  = (const float*)d_in[2];
    const float* w1  = (const float*)d_in[3];
    const float* b1  = (const float*)d_in[4];
    const float* lng1 = (const float*)d_in[5];
    const float* lnb1 = (const float*)d_in[6];
    const float* w2  = (const float*)d_in[7];
    const float* b2  = (const float*)d_in[8];
    const float* wq  = (const float*)d_in[9];
    const float* wk  = (const float*)d_in[10];
    const float* wv  = (const float*)d_in[11];
    const float* wo  = (const float*)d_in[12];
    const float* lng2 = (const float*)d_in[13];
    const float* lnb2 = (const float*)d_in[14];
    const float* ow  = (const float*)d_in[15];
    const float* ob  = (const float*)d_in[16];

    char* p = (char*)d_ws;
    auto take = [&](size_t bytes) {
        char* r = p;
        p += (bytes + 255) & ~(size_t)255;
        return r;
    };
    const size_t M = 16384;
    float* kern   = (float*)take(8 * 1024 * sizeof(float));
    float* coeffs = (float*)take(M * 8 * sizeof(float));
    bf16* g       = (bf16*)take(M * 512 * 2);
    bf16* mixed   = (bf16*)take(M * 1024 * 2);
    bf16* qb      = (bf16*)take(M * 1024 * 2 * 2);  // q followed by k; reused as o(f32) later
    bf16* kb2     = qb + M * 1024;
    float* o32    = (float*)qb;
    bf16* vtb     = (bf16*)take(M * 1024 * 2);      // v transposed per (chunk,head); reused as t later
    bf16* tb      = vtb;
    bf16* aob     = (bf16*)take(M * 1024 * 2);
    bf16* w2t     = (bf16*)take((size_t)1024 * 512 * 2);
    bf16* wqt     = (bf16*)take((size_t)1024 * 1024 * 2);
    bf16* wkt     = (bf16*)take((size_t)1024 * 1024 * 2);
    bf16* wvt     = (bf16*)take((size_t)1024 * 1024 * 2);
    bf16* wot     = (bf16*)take((size_t)1024 * 1024 * 2);
    bf16* owt     = (bf16*)take((size_t)256 * 1024 * 2);

    k_wavelet<<<8, 256, 0, stream>>>(mw, sc, kern);
    k_coeffs<<<4096, 256, 0, stream>>>(x, kern, coeffs);
    k_mix1<<<16384, 256, 0, stream>>>(coeffs, w1, b1, lng1, lnb1, g);

    k_wtrans<<<(512 * 1024) / 256, 256, 0, stream>>>(w2, w2t, 512, 1024);
    k_wtrans<<<(1024 * 1024) / 256, 256, 0, stream>>>(wq, wqt, 1024, 1024);
    k_wtrans<<<(1024 * 1024) / 256, 256, 0, stream>>>(wk, wkt, 1024, 1024);
    k_wtrans<<<(1024 * 1024) / 256, 256, 0, stream>>>(wv, wvt, 1024, 1024);
    k_wtrans<<<(1024 * 1024) / 256, 256, 0, stream>>>(wo, wot, 1024, 1024);
    k_wtrans<<<(1024 * 256) / 256, 256, 0, stream>>>(ow, owt, 1024, 256);

    // mixed = gelu(hid) @ w2 + b2
    k_gemm256<EPI_BF16_BIAS><<<dim3(4, 64), 512, 0, stream>>>(
        g, w2t, b2, mixed, 512, 512, 512, 1024, 1.f);
    // q (scaled by hd^-0.5), k, v(transposed layout)
    k_gemm256<EPI_BF16><<<dim3(4, 64), 512, 0, stream>>>(
        mixed, wqt, nullptr, qb, 1024, 1024, 1024, 1024, 0.0625f);
    k_gemm256<EPI_BF16><<<dim3(4, 64), 512, 0, stream>>>(
        mixed, wkt, nullptr, kb2, 1024, 1024, 1024, 1024, 1.f);
    k_gemm256<EPI_VT><<<dim3(4, 64), 512, 0, stream>>>(
        mixed, wvt, nullptr, vtb, 1024, 1024, 1024, 1024, 1.f);
    // attention
    k_attn<<<dim3(16, 4, 16), 256, 0, stream>>>(qb, kb2, vtb, aob);
    // o = ao @ wo (fp32, overwrites q+k region)
    k_gemm256<EPI_F32><<<dim3(4, 64), 512, 0, stream>>>(
        aob, wot, nullptr, o32, 1024, 1024, 1024, 1024, 1.f);
    // t = LN(o + mixed) (overwrites vt region)
    k_outln<<<16384, 256, 0, stream>>>(o32, mixed, lng2, lnb2, tb);
    // y = t @ out_w + out_b (N=256 -> keep 128^2 kernel, grid 256 blocks)
    k_gemm<EPI_F32_BIAS><<<dim3(2, 128), 256, 0, stream>>>(
        tb, owt, ob, d_out, 16384, 256, 1024, 1024, 1024, 256, 1.f);
}

// Round 4
// 476.787 us; speedup vs baseline: 1.2208x; 1.0714x over previous
//
#include <hip/hip_runtime.h>
#include <hip/hip_bf16.h>

typedef __bf16 bf16;
typedef __bf16 bf16x8 __attribute__((ext_vector_type(8)));
typedef float f32x4 __attribute__((ext_vector_type(4)));
typedef unsigned short ushort8_t __attribute__((ext_vector_type(8)));

#define GLOAD_LDS16(g, l)                                                      \
    __builtin_amdgcn_global_load_lds(                                          \
        (const __attribute__((address_space(1))) void*)(g),                    \
        (__attribute__((address_space(3))) void*)(l), 16, 0, 0)

// Problem constants
// B=4, S=4096, H=1024, G=256, W=8, CHUNK=1024, NUM_HEADS=4, hd=256
// M = B*S = 16384 rows, NC = 16 chunks

// ---------------- wavelet kernel normalization ----------------
__global__ __launch_bounds__(256) void k_wavelet(const float* __restrict__ mw,
                                                 const float* __restrict__ sc,
                                                 float* __restrict__ kern) {
    int w = blockIdx.x;
    int tid = threadIdx.x;
    float s = 0.f;
    for (int h = tid; h < 1024; h += 256) { float v = mw[w * 1024 + h]; s += v * v; }
#pragma unroll
    for (int xm = 1; xm < 64; xm <<= 1) s += __shfl_xor(s, xm);
    __shared__ float red[4];
    if ((tid & 63) == 0) red[tid >> 6] = s;
    __syncthreads();
    float tot = red[0] + red[1] + red[2] + red[3];
    float inv = 1.f / fmaxf(sqrtf(tot), 1e-12f);
    float sg = 1.f / (1.f + __expf(-sc[w]));
    float m = inv * sg;
    for (int h = tid; h < 1024; h += 256) kern[w * 1024 + h] = mw[w * 1024 + h] * m;
}

// ---------------- coeffs = xc @ kern^T  (16384 x 8) ----------------
__global__ __launch_bounds__(256) void k_coeffs(const float* __restrict__ x,
                                                const float* __restrict__ kern,
                                                float* __restrict__ coeffs) {
    __shared__ float kl[8 * 1024];
    int tid = threadIdx.x;
    for (int i = tid; i < 8192; i += 256) kl[i] = kern[i];
    __syncthreads();
    int wid = tid >> 6, lane = tid & 63;
    long row = (long)blockIdx.x * 4 + wid;
    float acc[8] = {0, 0, 0, 0, 0, 0, 0, 0};
    const float* xr = x + row * 1024;
    for (int i = 0; i < 16; i++) {
        float xv = xr[lane + i * 64];
#pragma unroll
        for (int w = 0; w < 8; w++) acc[w] += xv * kl[w * 1024 + lane + i * 64];
    }
#pragma unroll
    for (int xm = 1; xm < 64; xm <<= 1) {
#pragma unroll
        for (int w = 0; w < 8; w++) acc[w] += __shfl_xor(acc[w], xm);
    }
    if (lane == 0) {
#pragma unroll
        for (int w = 0; w < 8; w++) coeffs[row * 8 + w] = acc[w];
    }
}

// ---------------- hid = LN(coeffs@w1 + b1); g = gelu(hid) (bf16) ----------------
__global__ __launch_bounds__(256) void k_mix1(const float* __restrict__ coeffs,
                                              const float* __restrict__ w1,
                                              const float* __restrict__ b1,
                                              const float* __restrict__ lng,
                                              const float* __restrict__ lnb,
                                              bf16* __restrict__ g) {
    long row = blockIdx.x;
    int tid = threadIdx.x;
    int wid = tid >> 6, lane = tid & 63;
    __shared__ float cf[8];
    __shared__ float red1[4], red2[4];
    if (tid < 8) cf[tid] = coeffs[row * 8 + tid];
    __syncthreads();
    float h0[2];
#pragma unroll
    for (int t = 0; t < 2; t++) {
        int j = tid + t * 256;
        float a = b1[j];
#pragma unroll
        for (int w = 0; w < 8; w++) a += cf[w] * w1[w * 512 + j];
        h0[t] = a;
    }
    float s1 = h0[0] + h0[1];
    float s2 = h0[0] * h0[0] + h0[1] * h0[1];
#pragma unroll
    for (int xm = 1; xm < 64; xm <<= 1) {
        s1 += __shfl_xor(s1, xm);
        s2 += __shfl_xor(s2, xm);
    }
    if (lane == 0) { red1[wid] = s1; red2[wid] = s2; }
    __syncthreads();
    s1 = red1[0] + red1[1] + red1[2] + red1[3];
    s2 = red2[0] + red2[1] + red2[2] + red2[3];
    float mean = s1 * (1.f / 512.f);
    float var = s2 * (1.f / 512.f) - mean * mean;
    float inv = rsqrtf(var + 1e-5f);
#pragma unroll
    for (int t = 0; t < 2; t++) {
        int j = tid + t * 256;
        float xn = (h0[t] - mean) * inv * lng[j] + lnb[j];
        float ge = 0.5f * xn * (1.f + erff(xn * 0.70710678118654752f));
        g[row * 512 + j] = (bf16)ge;
    }
}

// ---------------- weight transpose + bf16 convert: wt[n][k] = w[k][n] ----------------
__global__ void k_wtrans(const float* __restrict__ w, bf16* __restrict__ wt, int K, int N) {
    long idx = (long)blockIdx.x * 256 + threadIdx.x;
    if (idx < (long)K * N) {
        int kk = (int)(idx / N);
        int n = (int)(idx % N);
        wt[(long)n * K + kk] = (bf16)w[idx];
    }
}

enum { EPI_BF16 = 0, EPI_BF16_BIAS = 1, EPI_F32_BIAS = 2, EPI_VT = 3, EPI_F32 = 4 };

// ---------------- GEMM 256x256, 8 waves, BK=64, 2-phase double-buffer ----------------
template <int EPI>
__global__ __launch_bounds__(512, 2) void k_gemm256(const bf16* __restrict__ A,
                                                    const bf16* __restrict__ Bt,
                                                    const float* __restrict__ bias,
                                                    void* __restrict__ Cout,
                                                    int K, int lda, int ldb, int ldc,
                                                    float scale) {
    __shared__ bf16 As[2 * 256 * 64];
    __shared__ bf16 Bs[2 * 256 * 64];
    int tid = threadIdx.x;
    int wid = tid >> 6, lane = tid & 63;
    int wr = wid >> 2, wc = wid & 3;  // 2 x 4 wave grid; wave owns 128x64 output
    long m0 = (long)blockIdx.y * 256, n0 = (long)blockIdx.x * 256;
    f32x4 acc[8][4] = {};
    const int lr = lane & 15, ko = (lane >> 4) << 3;

    const int grow = wid * 8 + (lane >> 3);
    const int gcol = (lane & 7) << 3;
    const bf16* aS = A + (m0 + grow) * lda + gcol;
    const bf16* bS = Bt + (n0 + grow) * ldb + gcol;
    bf16* lA = As + wid * 512;
    bf16* lB = Bs + wid * 512;

    const int nt = K >> 6;
#pragma unroll
    for (int i = 0; i < 4; i++) {
        GLOAD_LDS16(aS + (long)(i * 64) * lda, lA + i * 4096);
        GLOAD_LDS16(bS + (long)(i * 64) * ldb, lB + i * 4096);
    }
    __syncthreads();
    int buf = 0;
    for (int t = 0; t < nt; t++) {
        if (t + 1 < nt) {
            const int k0 = (t + 1) << 6;
            const int ob = (buf ^ 1) << 14;
#pragma unroll
            for (int i = 0; i < 4; i++) {
                GLOAD_LDS16(aS + (long)(i * 64) * lda + k0, lA + ob + i * 4096);
                GLOAD_LDS16(bS + (long)(i * 64) * ldb + k0, lB + ob + i * 4096);
            }
        }
        const bf16* At = As + (buf << 14);
        const bf16* Bb = Bs + (buf << 14);
#pragma unroll
        for (int kk = 0; kk < 2; kk++) {
            bf16x8 af[8], bfr[4];
#pragma unroll
            for (int i = 0; i < 8; i++)
                af[i] = *(const bf16x8*)&At[(wr * 128 + i * 16 + lr) * 64 + kk * 32 + ko];
#pragma unroll
            for (int j = 0; j < 4; j++)
                bfr[j] = *(const bf16x8*)&Bb[(wc * 64 + j * 16 + lr) * 64 + kk * 32 + ko];
#pragma unroll
            for (int i = 0; i < 8; i++) {
#pragma unroll
                for (int j = 0; j < 4; j++)
                    acc[i][j] = __builtin_amdgcn_mfma_f32_16x16x32_bf16(af[i], bfr[j], acc[i][j], 0, 0, 0);
            }
        }
        __syncthreads();
        buf ^= 1;
    }
    const int r0 = (lane >> 4) << 2;
#pragma unroll
    for (int i = 0; i < 8; i++) {
#pragma unroll
        for (int j = 0; j < 4; j++) {
#pragma unroll
            for (int e = 0; e < 4; e++) {
                long m = m0 + wr * 128 + i * 16 + r0 + e;
                long n = n0 + wc * 64 + j * 16 + lr;
                float v = acc[i][j][e] * scale;
                if constexpr (EPI == EPI_BF16_BIAS || EPI == EPI_F32_BIAS) v += bias[n];
                if constexpr (EPI == EPI_F32_BIAS || EPI == EPI_F32) {
                    ((float*)Cout)[m * ldc + n] = v;
                } else if constexpr (EPI == EPI_VT) {
                    long c = m >> 10, s = m & 1023, h = n >> 8, d = n & 255;
                    ((bf16*)Cout)[(((c << 2) + h) << 18) + (d << 10) + s] = (bf16)v;
                } else {
                    ((bf16*)Cout)[m * ldc + n] = (bf16)v;
                }
            }
        }
    }
}

// ---------------- GEMM 128x128 (m97 structure) — for the N=256 final GEMM ----------------
template <int EPI>
__global__ __launch_bounds__(256) void k_gemm(const bf16* __restrict__ A,
                                              const bf16* __restrict__ Bt,
                                              const float* __restrict__ bias,
                                              void* __restrict__ Cout,
                                              int M, int N, int K,
                                              int lda, int ldb, int ldc, float scale) {
    __shared__ bf16 As[128 * 32];
    __shared__ bf16 Bs[128 * 32];
    int tid = threadIdx.x;
    int wid = tid >> 6, lane = tid & 63;
    int wr = wid >> 1, wc = wid & 1;
    long m0 = (long)blockIdx.y * 128, n0 = (long)blockIdx.x * 128;
    f32x4 acc[4][4] = {};
    const int lr = lane & 15, ko = (lane >> 4) << 3;

    const int srow = wid * 32 + (lane >> 2);
    const int scol = (lane & 3) << 3;
    const bf16* a0 = A + (m0 + srow) * lda + scol;
    const bf16* a1 = A + (m0 + srow + 16) * lda + scol;
    const bf16* b0 = Bt + (n0 + srow) * ldb + scol;
    const bf16* b1 = Bt + (n0 + srow + 16) * ldb + scol;
    bf16* la0 = As + wid * 1024;
    bf16* la1 = As + wid * 1024 + 512;
    bf16* lb0 = Bs + wid * 1024;
    bf16* lb1 = Bs + wid * 1024 + 512;

    for (int k0 = 0; k0 < K; k0 += 32) {
        GLOAD_LDS16(a0 + k0, la0);
        GLOAD_LDS16(a1 + k0, la1);
        GLOAD_LDS16(b0 + k0, lb0);
        GLOAD_LDS16(b1 + k0, lb1);
        __syncthreads();
        bf16x8 af[4], bfr[4];
#pragma unroll
        for (int i = 0; i < 4; i++)
            af[i] = *(const bf16x8*)&As[(wr * 64 + i * 16 + lr) * 32 + ko];
#pragma unroll
        for (int i = 0; i < 4; i++)
            bfr[i] = *(const bf16x8*)&Bs[(wc * 64 + i * 16 + lr) * 32 + ko];
#pragma unroll
        for (int i = 0; i < 4; i++) {
#pragma unroll
            for (int j = 0; j < 4; j++)
                acc[i][j] = __builtin_amdgcn_mfma_f32_16x16x32_bf16(af[i], bfr[j], acc[i][j], 0, 0, 0);
        }
        __syncthreads();
    }
    const int r0 = (lane >> 4) << 2;
#pragma unroll
    for (int i = 0; i < 4; i++) {
#pragma unroll
        for (int j = 0; j < 4; j++) {
#pragma unroll
            for (int e = 0; e < 4; e++) {
                long m = m0 + wr * 64 + i * 16 + r0 + e;
                long n = n0 + wc * 64 + j * 16 + lr;
                float v = acc[i][j][e] * scale;
                if constexpr (EPI == EPI_BF16_BIAS || EPI == EPI_F32_BIAS) v += bias[n];
                if constexpr (EPI == EPI_F32_BIAS || EPI == EPI_F32) {
                    ((float*)Cout)[m * ldc + n] = v;
                } else if constexpr (EPI == EPI_VT) {
                    long c = m >> 10, s = m & 1023, h = n >> 8, d = n & 255;
                    ((bf16*)Cout)[(((c << 2) + h) << 18) + (d << 10) + s] = (bf16)v;
                } else {
                    ((bf16*)Cout)[m * ldc + n] = (bf16)v;
                }
            }
        }
    }
}

// ---------------- flash attention: 8 waves, 128 q-rows/block, gload_lds + XOR swizzle ----------------
// grid (16 chunks, 4 heads, 8 qblocks): the 8 blocks sharing one (c,h) K/V have
// dispatch ids congruent mod 8 -> same XCD under round-robin -> L2 reuse.
// LDS: K 2x[64][256] + V 2x[256][64] + P 8x[16][64], all linear; physical granule
// p = logical_granule ^ (row&7) (source-preswizzled for gload_lds; read-swizzled).
__global__ __launch_bounds__(512, 2) void k_attn(const bf16* __restrict__ q,
                                                 const bf16* __restrict__ k,
                                                 const bf16* __restrict__ vt,
                                                 bf16* __restrict__ ao) {
    __shared__ __align__(16) bf16 smem[2 * 16384 + 2 * 16384 + 8192];
    bf16* Ks = smem;            // [2][64][256]
    bf16* Vs = smem + 32768;    // [2][256][64]
    bf16* Ps = smem + 65536;    // [8][16][64]
    int tid = threadIdx.x;
    int wid = tid >> 6, lane = tid & 63;
    int c = blockIdx.x, h = blockIdx.y, q0 = blockIdx.z * 128;
    const int lr = lane & 15, gq = lane >> 4, ko = gq << 3;
    const int l7 = lr & 7;

    // K staging: issue i covers rows i*16 + krw; lane granule (lane&31), source col swizzled
    const int krw = wid * 2 + (lane >> 5);                 // 0..15
    const int kg = (lane & 31) ^ (krw & 7);
    const bf16* ksrc = k + ((long)c << 10) * 1024 + h * 256 + kg * 8;
    // V staging: issue i covers rows i*64 + vrw
    const int vrw = wid * 8 + ((lane >> 3) & 7);           // 0..63
    const int vg = (lane & 7) ^ ((lane >> 3) & 7);
    const bf16* vsrc = vt + ((long)(c * 4 + h) << 18) + vg * 8;

    long qrow = ((long)c << 10) + q0 + wid * 16 + lr;
    bf16x8 qf[8];
#pragma unroll
    for (int kk = 0; kk < 8; kk++)
        qf[kk] = *(const bf16x8*)&q[qrow * 1024 + h * 256 + kk * 32 + ko];

    f32x4 oacc[16] = {};
    float m_run[4] = {-1e30f, -1e30f, -1e30f, -1e30f};
    float l_run[4] = {0.f, 0.f, 0.f, 0.f};

    // prologue: stage kb=0 into buf 0
#pragma unroll
    for (int i = 0; i < 4; i++) {
        GLOAD_LDS16(ksrc + (long)(i * 16 + krw) * 1024, Ks + i * 4096 + wid * 512);
        GLOAD_LDS16(vsrc + (long)(i * 64 + vrw) * 1024, Vs + i * 4096 + wid * 512);
    }
    __syncthreads();
    int buf = 0;
    for (int t = 0; t < 16; t++) {
        if (t < 15) {
            const int kb = (t + 1) << 6;
            const int ob = (buf ^ 1) << 14;
#pragma unroll
            for (int i = 0; i < 4; i++) {
                GLOAD_LDS16(ksrc + (long)(kb + i * 16 + krw) * 1024, Ks + ob + i * 4096 + wid * 512);
                GLOAD_LDS16(vsrc + (long)(i * 64 + vrw) * 1024 + kb, Vs + ob + i * 4096 + wid * 512);
            }
        }
        const bf16* Kc = Ks + (buf << 14);
        const bf16* Vc = Vs + (buf << 14);
        f32x4 s[4] = {};
        __builtin_amdgcn_s_setprio(1);
#pragma unroll
        for (int kk = 0; kk < 8; kk++) {
#pragma unroll
            for (int n = 0; n < 4; n++)
                s[n] = __builtin_amdgcn_mfma_f32_16x16x32_bf16(
                    qf[kk],
                    *(const bf16x8*)&Kc[((n * 16 + lr) << 8) + ((((kk << 2) + gq) ^ l7) << 3)],
                    s[n], 0, 0, 0);
        }
        __builtin_amdgcn_s_setprio(0);
        float mx[4], al[4], rs[4];
#pragma unroll
        for (int e = 0; e < 4; e++)
            mx[e] = fmaxf(fmaxf(s[0][e], s[1][e]), fmaxf(s[2][e], s[3][e]));
#pragma unroll
        for (int xm = 1; xm < 16; xm <<= 1) {
#pragma unroll
            for (int e = 0; e < 4; e++) mx[e] = fmaxf(mx[e], __shfl_xor(mx[e], xm));
        }
#pragma unroll
        for (int e = 0; e < 4; e++) {
            float mn = fmaxf(m_run[e], mx[e]);
            al[e] = __expf(m_run[e] - mn);
            m_run[e] = mn;
            rs[e] = 0.f;
        }
#pragma unroll
        for (int n = 0; n < 4; n++) {
#pragma unroll
            for (int e = 0; e < 4; e++) {
                float p = __expf(s[n][e] - m_run[e]);
                s[n][e] = p;
                rs[e] += p;
            }
        }
#pragma unroll
        for (int xm = 1; xm < 16; xm <<= 1) {
#pragma unroll
            for (int e = 0; e < 4; e++) rs[e] += __shfl_xor(rs[e], xm);
        }
#pragma unroll
        for (int e = 0; e < 4; e++) l_run[e] = l_run[e] * al[e] + rs[e];
#pragma unroll
        for (int f = 0; f < 16; f++) {
#pragma unroll
            for (int e = 0; e < 4; e++) oacc[f][e] *= al[e];
        }
        // P write (per-wave private region; lgkmcnt orders write->read, no barrier)
#pragma unroll
        for (int n = 0; n < 4; n++) {
#pragma unroll
            for (int e = 0; e < 4; e++) {
                const int rw = (gq << 2) + e;
                Ps[(wid << 10) + (rw << 6) + ((((n << 1) + (lr >> 3)) ^ (rw & 7)) << 3) + (lr & 7)] =
                    (bf16)s[n][e];
            }
        }
        const int pg = gq ^ l7;
        bf16x8 pf0 = *(const bf16x8*)&Ps[(wid << 10) + (lr << 6) + (pg << 3)];
        bf16x8 pf1 = *(const bf16x8*)&Ps[(wid << 10) + (lr << 6) + ((pg ^ 4) << 3)];
        __builtin_amdgcn_s_setprio(1);
#pragma unroll
        for (int n2 = 0; n2 < 16; n2++) {
            const int vrow = (n2 * 16 + lr) << 6;
            const int vswz = gq ^ l7;
            oacc[n2] = __builtin_amdgcn_mfma_f32_16x16x32_bf16(
                pf0, *(const bf16x8*)&Vc[vrow + (vswz << 3)], oacc[n2], 0, 0, 0);
            oacc[n2] = __builtin_amdgcn_mfma_f32_16x16x32_bf16(
                pf1, *(const bf16x8*)&Vc[vrow + ((vswz ^ 4) << 3)], oacc[n2], 0, 0, 0);
        }
        __builtin_amdgcn_s_setprio(0);
        __syncthreads();
        buf ^= 1;
    }
#pragma unroll
    for (int n2 = 0; n2 < 16; n2++) {
#pragma unroll
        for (int e = 0; e < 4; e++) {
            long row = ((long)c << 10) + q0 + wid * 16 + (gq << 2) + e;
            long col = ((long)h << 8) + n2 * 16 + lr;
            ao[row * 1024 + col] = (bf16)(oacc[n2][e] / l_run[e]);
        }
    }
}

// ---------------- t = LN(o + mixed) (bf16) ----------------
__global__ __launch_bounds__(256) void k_outln(const float* __restrict__ o,
                                               const bf16* __restrict__ mixed,
                                               const float* __restrict__ g,
                                               const float* __restrict__ b,
                                               bf16* __restrict__ t) {
    long row = blockIdx.x;
    int tid = threadIdx.x;
    int wid = tid >> 6, lane = tid & 63;
    __shared__ float red1[4], red2[4];
    float x[4];
    const float* orow = o + row * 1024;
    const bf16* mrow = mixed + row * 1024;
#pragma unroll
    for (int i = 0; i < 4; i++) {
        int j = tid * 4 + i;
        x[i] = orow[j] + (float)mrow[j];
    }
    float s1 = x[0] + x[1] + x[2] + x[3];
    float s2 = x[0] * x[0] + x[1] * x[1] + x[2] * x[2] + x[3] * x[3];
#pragma unroll
    for (int xm = 1; xm < 64; xm <<= 1) {
        s1 += __shfl_xor(s1, xm);
        s2 += __shfl_xor(s2, xm);
    }
    if (lane == 0) { red1[wid] = s1; red2[wid] = s2; }
    __syncthreads();
    s1 = red1[0] + red1[1] + red1[2] + red1[3];
    s2 = red2[0] + red2[1] + red2[2] + red2[3];
    float mean = s1 * (1.f / 1024.f);
    float var = s2 * (1.f / 1024.f) - mean * mean;
    float inv = rsqrtf(var + 1e-5f);
#pragma unroll
    for (int i = 0; i < 4; i++) {
        int j = tid * 4 + i;
        t[row * 1024 + j] = (bf16)((x[i] - mean) * inv * g[j] + b[j]);
    }
}

extern "C" void kernel_launch(void* const* d_in, const int* in_sizes, int n_in,
                              void* d_out, int out_size, void* d_ws, size_t ws_size,
                              hipStream_t stream) {
    const float* x   = (const float*)d_in[0];
    const float* mw  = (const float*)d_in[1];
    const float* sc  = (const float*)d_in[2];
    const float* w1  = (const float*)d_in[3];
    const float* b1  = (const float*)d_in[4];
    const float* lng1 = (const float*)d_in[5];
    const float* lnb1 = (const float*)d_in[6];
    const float* w2  = (const float*)d_in[7];
    const float* b2  = (const float*)d_in[8];
    const float* wq  = (const float*)d_in[9];
    const float* wk  = (const float*)d_in[10];
    const float* wv  = (const float*)d_in[11];
    const float* wo  = (const float*)d_in[12];
    const float* lng2 = (const float*)d_in[13];
    const float* lnb2 = (const float*)d_in[14];
    const float* ow  = (const float*)d_in[15];
    const float* ob  = (const float*)d_in[16];

    char* p = (char*)d_ws;
    auto take = [&](size_t bytes) {
        char* r = p;
        p += (bytes + 255) & ~(size_t)255;
        return r;
    };
    const size_t M = 16384;
    float* kern   = (float*)take(8 * 1024 * sizeof(float));
    float* coeffs = (float*)take(M * 8 * sizeof(float));
    bf16* g       = (bf16*)take(M * 512 * 2);
    bf16* mixed   = (bf16*)take(M * 1024 * 2);
    bf16* qb      = (bf16*)take(M * 1024 * 2 * 2);  // q followed by k; reused as o(f32) later
    bf16* kb2     = qb + M * 1024;
    float* o32    = (float*)qb;
    bf16* vtb     = (bf16*)take(M * 1024 * 2);      // v transposed per (chunk,head); reused as t later
    bf16* tb      = vtb;
    bf16* aob     = (bf16*)take(M * 1024 * 2);
    bf16* w2t     = (bf16*)take((size_t)1024 * 512 * 2);
    bf16* wqt     = (bf16*)take((size_t)1024 * 1024 * 2);
    bf16* wkt     = (bf16*)take((size_t)1024 * 1024 * 2);
    bf16* wvt     = (bf16*)take((size_t)1024 * 1024 * 2);
    bf16* wot     = (bf16*)take((size_t)1024 * 1024 * 2);
    bf16* owt     = (bf16*)take((size_t)256 * 1024 * 2);

    k_wavelet<<<8, 256, 0, stream>>>(mw, sc, kern);
    k_coeffs<<<4096, 256, 0, stream>>>(x, kern, coeffs);
    k_mix1<<<16384, 256, 0, stream>>>(coeffs, w1, b1, lng1, lnb1, g);

    k_wtrans<<<(512 * 1024) / 256, 256, 0, stream>>>(w2, w2t, 512, 1024);
    k_wtrans<<<(1024 * 1024) / 256, 256, 0, stream>>>(wq, wqt, 1024, 1024);
    k_wtrans<<<(1024 * 1024) / 256, 256, 0, stream>>>(wk, wkt, 1024, 1024);
    k_wtrans<<<(1024 * 1024) / 256, 256, 0, stream>>>(wv, wvt, 1024, 1024);
    k_wtrans<<<(1024 * 1024) / 256, 256, 0, stream>>>(wo, wot, 1024, 1024);
    k_wtrans<<<(1024 * 256) / 256, 256, 0, stream>>>(ow, owt, 1024, 256);

    // mixed = gelu(hid) @ w2 + b2
    k_gemm256<EPI_BF16_BIAS><<<dim3(4, 64), 512, 0, stream>>>(
        g, w2t, b2, mixed, 512, 512, 512, 1024, 1.f);
    // q (scaled by hd^-0.5), k, v(transposed layout)
    k_gemm256<EPI_BF16><<<dim3(4, 64), 512, 0, stream>>>(
        mixed, wqt, nullptr, qb, 1024, 1024, 1024, 1024, 0.0625f);
    k_gemm256<EPI_BF16><<<dim3(4, 64), 512, 0, stream>>>(
        mixed, wkt, nullptr, kb2, 1024, 1024, 1024, 1024, 1.f);
    k_gemm256<EPI_VT><<<dim3(4, 64), 512, 0, stream>>>(
        mixed, wvt, nullptr, vtb, 1024, 1024, 1024, 1024, 1.f);
    // attention (8 waves, 128 q-rows per block)
    k_attn<<<dim3(16, 4, 8), 512, 0, stream>>>(qb, kb2, vtb, aob);
    // o = ao @ wo (fp32, overwrites q+k region)
    k_gemm256<EPI_F32><<<dim3(4, 64), 512, 0, stream>>>(
        aob, wot, nullptr, o32, 1024, 1024, 1024, 1024, 1.f);
    // t = LN(o + mixed) (overwrites vt region)
    k_outln<<<16384, 256, 0, stream>>>(o32, mixed, lng2, lnb2, tb);
    // y = t @ out_w + out_b (N=256 -> 128^2 kernel, grid 256 blocks)
    k_gemm<EPI_F32_BIAS><<<dim3(2, 128), 256, 0, stream>>>(
        tb, owt, ob, d_out, 16384, 256, 1024, 1024, 1024, 256, 1.f);
}